// Round 2
// baseline (886.072 us; speedup 1.0000x reference)
//
#include <hip/hip_runtime.h>

// GCN VGAE encoder: 3x GCNConv on N=50000 nodes, E=1.6M edges (+self-loops).
// Algebraic fusion: aggregate(x@W) == aggregate(x)@W, so layers 2&3 share ONE
// 64-channel aggregation of h, followed by two tiny GEMMs.
// NOTE: harness passes integer inputs as int32 (edge_index -> const int*).

__global__ void k_init_deg(float* __restrict__ deg, int n) {
    int i = blockIdx.x * blockDim.x + threadIdx.x;
    if (i < n) deg[i] = 1.0f;  // self-loop contribution
}

__global__ void k_deg(const int* __restrict__ col, float* __restrict__ deg, int e) {
    int i = blockIdx.x * blockDim.x + threadIdx.x;
    if (i < e) atomicAdd(deg + col[i], 1.0f);
}

__global__ void k_dis(float* __restrict__ deg, int n) {
    int i = blockIdx.x * blockDim.x + threadIdx.x;
    if (i < n) deg[i] = rsqrtf(deg[i]);
}

// x[n,128] @ W[128,64] -> out[n,64]. Block = 256 threads = 4 rows x 64 cols.
__global__ __launch_bounds__(256) void k_gemm1(const float* __restrict__ x,
                                               const float* __restrict__ W,
                                               float* __restrict__ out, int n) {
    __shared__ float w[128 * 64];
    for (int i = threadIdx.x; i < 128 * 64; i += 256) w[i] = W[i];
    __syncthreads();
    int row = blockIdx.x * 4 + (threadIdx.x >> 6);
    int col = threadIdx.x & 63;
    if (row >= n) return;
    const float4* xr = (const float4*)(x + row * 128);
    float acc = 0.f;
#pragma unroll
    for (int k4 = 0; k4 < 32; ++k4) {
        float4 xv = xr[k4];  // broadcast across the 64 lanes of this row-group
        int k = k4 * 4;
        acc += xv.x * w[k * 64 + col] + xv.y * w[(k + 1) * 64 + col] +
               xv.z * w[(k + 2) * 64 + col] + xv.w * w[(k + 3) * 64 + col];
    }
    out[row * 64 + col] = acc;
}

// dst[i,c] = dis[i]^2 * src[i,c]   (self-loop term, also zero-initializes dst)
__global__ void k_selfinit(const float* __restrict__ src, const float* __restrict__ dis,
                           float* __restrict__ dst, int n) {
    int t = blockIdx.x * blockDim.x + threadIdx.x;
    if (t >= n * 64) return;
    float d = dis[t >> 6];
    dst[t] = d * d * src[t];
}

// 64 lanes per edge: dst[c,ch] += dis[r]*dis[c] * src[r,ch]
__global__ __launch_bounds__(256) void k_scatter(const int* __restrict__ row,
                                                 const int* __restrict__ col,
                                                 const float* __restrict__ dis,
                                                 const float* __restrict__ src,
                                                 float* __restrict__ dst, int e) {
    int t = blockIdx.x * 256 + threadIdx.x;
    int eidx = t >> 6;
    int ch = t & 63;
    if (eidx >= e) return;
    int r = row[eidx];   // wave-uniform -> broadcast load
    int c = col[eidx];
    float nrm = dis[r] * dis[c];
    atomicAdd(dst + c * 64 + ch, nrm * src[r * 64 + ch]);
}

__global__ void k_biasrelu(float* __restrict__ h, const float* __restrict__ b, int n) {
    int t = blockIdx.x * blockDim.x + threadIdx.x;
    if (t >= n * 64) return;
    float v = h[t] + b[t & 63];
    h[t] = v > 0.f ? v : 0.f;
}

// g[n,64] @ {W2,W3}[64,32] + {b2,b3} -> out = mu (n*32) ++ logvar (n*32)
__global__ __launch_bounds__(256) void k_gemm23(const float* __restrict__ g,
                                                const float* __restrict__ W2,
                                                const float* __restrict__ b2,
                                                const float* __restrict__ W3,
                                                const float* __restrict__ b3,
                                                float* __restrict__ out, int n) {
    __shared__ float w2[64 * 32], w3[64 * 32];
    for (int i = threadIdx.x; i < 64 * 32; i += 256) { w2[i] = W2[i]; w3[i] = W3[i]; }
    __syncthreads();
    int row = blockIdx.x * 8 + (threadIdx.x >> 5);
    int col = threadIdx.x & 31;
    if (row >= n) return;
    const float* gr = g + row * 64;
    float a2 = 0.f, a3 = 0.f;
#pragma unroll
    for (int k = 0; k < 64; ++k) {
        float gv = gr[k];
        a2 += gv * w2[k * 32 + col];
        a3 += gv * w3[k * 32 + col];
    }
    out[row * 32 + col] = a2 + b2[col];
    out[n * 32 + row * 32 + col] = a3 + b3[col];
}

extern "C" void kernel_launch(void* const* d_in, const int* in_sizes, int n_in,
                              void* d_out, int out_size, void* d_ws, size_t ws_size,
                              hipStream_t stream) {
    const float* x  = (const float*)d_in[0];
    const int*   ei = (const int*)d_in[1];     // int32 per harness contract
    const float* W1 = (const float*)d_in[2];
    const float* b1 = (const float*)d_in[3];
    const float* W2 = (const float*)d_in[4];
    const float* b2 = (const float*)d_in[5];
    const float* W3 = (const float*)d_in[6];
    const float* b3 = (const float*)d_in[7];

    int n = in_sizes[0] / 128;   // 50000
    int e = in_sizes[1] / 2;     // 1600000
    const int* row = ei;         // edge_index[0]
    const int* col = ei + e;     // edge_index[1]

    float* ws    = (float*)d_ws;
    float* dis   = ws;                      // n      (deg -> deg_inv_sqrt in place)
    float* h_pre = ws + n;                  // n*64   x@W1
    float* hagg  = h_pre + (size_t)n * 64;  // n*64   aggregated, then relu'd h
    float* gagg  = hagg + (size_t)n * 64;   // n*64   aggregate of h
    float* out   = (float*)d_out;

    dim3 blk(256);
    k_init_deg<<<(n + 255) / 256, blk, 0, stream>>>(dis, n);
    k_deg<<<(e + 255) / 256, blk, 0, stream>>>(col, dis, e);
    k_dis<<<(n + 255) / 256, blk, 0, stream>>>(dis, n);

    k_gemm1<<<(n + 3) / 4, blk, 0, stream>>>(x, W1, h_pre, n);

    // layer 1 aggregation
    k_selfinit<<<(n * 64 + 255) / 256, blk, 0, stream>>>(h_pre, dis, hagg, n);
    k_scatter<<<(e * 64 + 255) / 256, blk, 0, stream>>>(row, col, dis, h_pre, hagg, e);
    k_biasrelu<<<(n * 64 + 255) / 256, blk, 0, stream>>>(hagg, b1, n);

    // shared aggregation for layers 2 & 3
    k_selfinit<<<(n * 64 + 255) / 256, blk, 0, stream>>>(hagg, dis, gagg, n);
    k_scatter<<<(e * 64 + 255) / 256, blk, 0, stream>>>(row, col, dis, hagg, gagg, e);

    k_gemm23<<<(n + 7) / 8, blk, 0, stream>>>(gagg, W2, b2, W3, b3, out, n);
}

// Round 3
// 546.009 us; speedup vs baseline: 1.6228x; 1.6228x over previous
//
#include <hip/hip_runtime.h>

// GCN VGAE encoder, pull-based. N=50000, E=1.6M, avg in-degree 32.
// out[i] = dis[i] * (hs[i] + sum_{j->i} hs[j]),  hs = dis .* (x@W)
// CSR built on-device (count -> scan -> fill), shared by both pulls.

__global__ void k_count(const int* __restrict__ col, int* __restrict__ cnt, int e) {
    int i = blockIdx.x * blockDim.x + threadIdx.x;
    if (i < e) atomicAdd(cnt + col[i], 1);
}

__global__ void k_dis(const int* __restrict__ cnt, float* __restrict__ dis, int n) {
    int i = blockIdx.x * blockDim.x + threadIdx.x;
    if (i < n) dis[i] = rsqrtf((float)cnt[i] + 1.0f);  // +1 = self-loop
}

// single-block exclusive scan of cnt[0..n) -> rowptr[0..n], cursor copy
__global__ __launch_bounds__(1024) void k_scan(const int* __restrict__ cnt,
                                               int* __restrict__ rowptr,
                                               int* __restrict__ cursor, int n) {
    __shared__ int s[1024];
    int t = threadIdx.x;
    int chunk = (n + 1023) / 1024;
    int beg = t * chunk;
    int end = beg + chunk < n ? beg + chunk : n;
    int sum = 0;
    for (int i = beg; i < end; ++i) sum += cnt[i];
    s[t] = sum;
    __syncthreads();
    for (int off = 1; off < 1024; off <<= 1) {
        int v = (t >= off) ? s[t - off] : 0;
        __syncthreads();
        s[t] += v;
        __syncthreads();
    }
    int run = (t == 0) ? 0 : s[t - 1];
    for (int i = beg; i < end; ++i) {
        int c = cnt[i];
        rowptr[i] = run;
        cursor[i] = run;
        run += c;
    }
    if (t == 1023) rowptr[n] = run;
}

__global__ void k_fill(const int* __restrict__ row, const int* __restrict__ col,
                       int* __restrict__ cursor, int* __restrict__ csr, int e) {
    int i = blockIdx.x * blockDim.x + threadIdx.x;
    if (i < e) {
        int pos = atomicAdd(cursor + col[i], 1);
        csr[pos] = row[i];
    }
}

// x[n,128] @ W[128,64], epilogue *dis  -> hs1[n,64]. 32 rows/block.
__global__ __launch_bounds__(256) void k_gemm1(const float* __restrict__ x,
                                               const float* __restrict__ W,
                                               const float* __restrict__ dis,
                                               float* __restrict__ hs1, int n) {
    __shared__ float w[128 * 64];
    for (int i = threadIdx.x; i < 128 * 64; i += 256) w[i] = W[i];
    __syncthreads();
    int ch = threadIdx.x & 63;
    int rbase = blockIdx.x * 32 + (threadIdx.x >> 6);
    for (int rr = 0; rr < 32; rr += 4) {
        int row = rbase + rr;
        if (row >= n) break;
        const float4* xr = (const float4*)(x + (size_t)row * 128);
        float acc = 0.f;
#pragma unroll
        for (int k4 = 0; k4 < 32; ++k4) {
            float4 xv = xr[k4];
            int k = k4 * 4;
            acc += xv.x * w[k * 64 + ch] + xv.y * w[(k + 1) * 64 + ch] +
                   xv.z * w[(k + 2) * 64 + ch] + xv.w * w[(k + 3) * 64 + ch];
        }
        hs1[(size_t)row * 64 + ch] = dis[row] * acc;
    }
}

// pull + relu(...+b1) + rescale: hs2[i] = dis[i]*relu(dis[i]*(hs1[i]+sum)+b1)
__global__ __launch_bounds__(256) void k_pull1(const int* __restrict__ rowptr,
                                               const int* __restrict__ csr,
                                               const float* __restrict__ hs1,
                                               const float* __restrict__ dis,
                                               const float* __restrict__ b1,
                                               float* __restrict__ hs2, int n) {
    int node = blockIdx.x * 4 + (threadIdx.x >> 6);
    int ch = threadIdx.x & 63;
    if (node >= n) return;
    int beg = rowptr[node], end = rowptr[node + 1];
    float a0 = hs1[(size_t)node * 64 + ch], a1 = 0.f, a2 = 0.f, a3 = 0.f;
    int k = beg;
    for (; k + 4 <= end; k += 4) {
        int s0 = csr[k], s1 = csr[k + 1], s2 = csr[k + 2], s3 = csr[k + 3];
        a0 += hs1[(size_t)s0 * 64 + ch];
        a1 += hs1[(size_t)s1 * 64 + ch];
        a2 += hs1[(size_t)s2 * 64 + ch];
        a3 += hs1[(size_t)s3 * 64 + ch];
    }
    for (; k < end; ++k) a0 += hs1[(size_t)csr[k] * 64 + ch];
    float d = dis[node];
    float v = d * ((a0 + a1) + (a2 + a3)) + b1[ch];
    hs2[(size_t)node * 64 + ch] = d * (v > 0.f ? v : 0.f);
}

// pull: gagg[i] = dis[i]*(hs2[i]+sum)
__global__ __launch_bounds__(256) void k_pull2(const int* __restrict__ rowptr,
                                               const int* __restrict__ csr,
                                               const float* __restrict__ hs2,
                                               const float* __restrict__ dis,
                                               float* __restrict__ gagg, int n) {
    int node = blockIdx.x * 4 + (threadIdx.x >> 6);
    int ch = threadIdx.x & 63;
    if (node >= n) return;
    int beg = rowptr[node], end = rowptr[node + 1];
    float a0 = hs2[(size_t)node * 64 + ch], a1 = 0.f, a2 = 0.f, a3 = 0.f;
    int k = beg;
    for (; k + 4 <= end; k += 4) {
        int s0 = csr[k], s1 = csr[k + 1], s2 = csr[k + 2], s3 = csr[k + 3];
        a0 += hs2[(size_t)s0 * 64 + ch];
        a1 += hs2[(size_t)s1 * 64 + ch];
        a2 += hs2[(size_t)s2 * 64 + ch];
        a3 += hs2[(size_t)s3 * 64 + ch];
    }
    for (; k < end; ++k) a0 += hs2[(size_t)csr[k] * 64 + ch];
    gagg[(size_t)node * 64 + ch] = dis[node] * ((a0 + a1) + (a2 + a3));
}

// g[n,64] @ {W2,W3}[64,32] + bias -> out = mu ++ logvar. 64 rows/block.
__global__ __launch_bounds__(256) void k_gemm23(const float* __restrict__ g,
                                                const float* __restrict__ W2,
                                                const float* __restrict__ b2,
                                                const float* __restrict__ W3,
                                                const float* __restrict__ b3,
                                                float* __restrict__ out, int n) {
    __shared__ float w2[64 * 32], w3[64 * 32];
    for (int i = threadIdx.x; i < 64 * 32; i += 256) { w2[i] = W2[i]; w3[i] = W3[i]; }
    __syncthreads();
    int col = threadIdx.x & 31;
    int rbase = blockIdx.x * 64 + (threadIdx.x >> 5);
    for (int rr = 0; rr < 64; rr += 8) {
        int row = rbase + rr;
        if (row >= n) break;
        const float* gr = g + (size_t)row * 64;
        float a2 = 0.f, a3 = 0.f;
#pragma unroll
        for (int k = 0; k < 64; ++k) {
            float gv = gr[k];
            a2 += gv * w2[k * 32 + col];
            a3 += gv * w3[k * 32 + col];
        }
        out[(size_t)row * 32 + col] = a2 + b2[col];
        out[(size_t)n * 32 + (size_t)row * 32 + col] = a3 + b3[col];
    }
}

extern "C" void kernel_launch(void* const* d_in, const int* in_sizes, int n_in,
                              void* d_out, int out_size, void* d_ws, size_t ws_size,
                              hipStream_t stream) {
    const float* x  = (const float*)d_in[0];
    const int*   ei = (const int*)d_in[1];   // int32 per harness contract
    const float* W1 = (const float*)d_in[2];
    const float* b1 = (const float*)d_in[3];
    const float* W2 = (const float*)d_in[4];
    const float* b2 = (const float*)d_in[5];
    const float* W3 = (const float*)d_in[6];
    const float* b3 = (const float*)d_in[7];

    int n = in_sizes[0] / 128;   // 50000
    int e = in_sizes[1] / 2;     // 1600000
    const int* row = ei;
    const int* col = ei + e;

    float* fws  = (float*)d_ws;
    float* dis  = fws;                        // n
    float* hs1  = fws + n;                    // n*64
    float* hs2  = hs1 + (size_t)n * 64;       // n*64
    float* gagg = hs1;                        // alias: hs1 dead after pull1
    int* cnt    = (int*)(hs2 + (size_t)n * 64);  // n
    int* cursor = cnt + n;                    // n
    int* rowptr = cursor + n;                 // n+1
    int* csr    = rowptr + n + 1;             // e

    dim3 blk(256);
    hipMemsetAsync(cnt, 0, (size_t)n * 4, stream);
    k_count<<<(e + 255) / 256, blk, 0, stream>>>(col, cnt, e);
    k_dis<<<(n + 255) / 256, blk, 0, stream>>>(cnt, dis, n);
    k_scan<<<1, 1024, 0, stream>>>(cnt, rowptr, cursor, n);
    k_fill<<<(e + 255) / 256, blk, 0, stream>>>(row, col, cursor, csr, e);

    k_gemm1<<<(n + 31) / 32, blk, 0, stream>>>(x, W1, dis, hs1, n);
    k_pull1<<<(n + 3) / 4, blk, 0, stream>>>(rowptr, csr, hs1, dis, b1, hs2, n);
    k_pull2<<<(n + 3) / 4, blk, 0, stream>>>(rowptr, csr, hs2, dis, gagg, n);
    k_gemm23<<<(n + 63) / 64, blk, 0, stream>>>(gagg, W2, b2, W3, b3, out_size ? (float*)d_out : (float*)d_out, n);
}

// Round 4
// 529.359 us; speedup vs baseline: 1.6739x; 1.0315x over previous
//
#include <hip/hip_runtime.h>

// GCN VGAE encoder, pull-based with bucketed CSR build.
// N=50000 (<2^16 -> rows pack in 16 bits), E=1.6M, avg in-degree 32.
// out[i] = dis[i] * (hs[i] + sum_{j->i} hs[j]),  hs = dis .* (x@W)

#define BKT 16  // nodes per bucket (col>>4)

__global__ void k_count(const int* __restrict__ col, int* __restrict__ cnt, int e) {
    int i = blockIdx.x * blockDim.x + threadIdx.x;
    if (i < e) atomicAdd(cnt + col[i], 1);
}

__global__ void k_dis(const int* __restrict__ cnt, float* __restrict__ dis, int n) {
    int i = blockIdx.x * blockDim.x + threadIdx.x;
    if (i < n) dis[i] = rsqrtf((float)cnt[i] + 1.0f);  // +1 = self-loop
}

// single-block exclusive scan of cnt[0..n) -> rowptr[0..n]
__global__ __launch_bounds__(1024) void k_scan(const int* __restrict__ cnt,
                                               int* __restrict__ rowptr, int n) {
    __shared__ int s[1024];
    int t = threadIdx.x;
    int chunk = (n + 1023) / 1024;
    int beg = t * chunk;
    int end = beg + chunk < n ? beg + chunk : n;
    int sum = 0;
    for (int i = beg; i < end; ++i) sum += cnt[i];
    s[t] = sum;
    __syncthreads();
    for (int off = 1; off < 1024; off <<= 1) {
        int v = (t >= off) ? s[t - off] : 0;
        __syncthreads();
        s[t] += v;
        __syncthreads();
    }
    int run = (t == 0) ? 0 : s[t - 1];
    for (int i = beg; i < end; ++i) {
        int c = cnt[i];
        rowptr[i] = run;
        run += c;
    }
    if (t == 1023) rowptr[n] = run;
}

__global__ void k_bcur(const int* __restrict__ rowptr, int* __restrict__ bcur, int nb) {
    int b = blockIdx.x * blockDim.x + threadIdx.x;
    if (b < nb) bcur[b] = rowptr[b * BKT];
}

// bin edges into per-bucket contiguous regions; pack (col&15)<<16 | row
__global__ void k_bin(const int* __restrict__ row, const int* __restrict__ col,
                      int* __restrict__ bcur, int* __restrict__ binbuf, int e) {
    int i = blockIdx.x * blockDim.x + threadIdx.x;
    if (i < e) {
        int c = col[i];
        int pos = atomicAdd(bcur + (c >> 4), 1);
        binbuf[pos] = row[i] | ((c & (BKT - 1)) << 16);
    }
}

// one block per bucket: LDS cursors, csr writes land in a ~2KB window
__global__ __launch_bounds__(256) void k_fill_bucket(const int* __restrict__ binbuf,
                                                     const int* __restrict__ rowptr,
                                                     int* __restrict__ csr, int n) {
    int node0 = blockIdx.x * BKT;
    int nloc = n - node0 < BKT ? n - node0 : BKT;
    __shared__ int cur[BKT];
    int beg = rowptr[node0];
    int end = rowptr[node0 + nloc];
    if (threadIdx.x < nloc) cur[threadIdx.x] = rowptr[node0 + threadIdx.x];
    __syncthreads();
    for (int k = beg + threadIdx.x; k < end; k += 256) {
        int p = binbuf[k];
        int pos = atomicAdd(&cur[p >> 16], 1);
        csr[pos] = p & 0xffff;
    }
}

// x[n,128] @ W[128,64], epilogue *dis  -> hs1[n,64]. 32 rows/block.
__global__ __launch_bounds__(256) void k_gemm1(const float* __restrict__ x,
                                               const float* __restrict__ W,
                                               const float* __restrict__ dis,
                                               float* __restrict__ hs1, int n) {
    __shared__ float w[128 * 64];
    for (int i = threadIdx.x; i < 128 * 64; i += 256) w[i] = W[i];
    __syncthreads();
    int ch = threadIdx.x & 63;
    int rbase = blockIdx.x * 32 + (threadIdx.x >> 6);
    for (int rr = 0; rr < 32; rr += 4) {
        int row = rbase + rr;
        if (row >= n) break;
        const float4* xr = (const float4*)(x + (size_t)row * 128);
        float acc = 0.f;
#pragma unroll
        for (int k4 = 0; k4 < 32; ++k4) {
            float4 xv = xr[k4];
            int k = k4 * 4;
            acc += xv.x * w[k * 64 + ch] + xv.y * w[(k + 1) * 64 + ch] +
                   xv.z * w[(k + 2) * 64 + ch] + xv.w * w[(k + 3) * 64 + ch];
        }
        hs1[(size_t)row * 64 + ch] = dis[row] * acc;
    }
}

// pull + relu(...+b1) + rescale: hs2[i] = dis[i]*relu(dis[i]*(hs1[i]+sum)+b1)
__global__ __launch_bounds__(256) void k_pull1(const int* __restrict__ rowptr,
                                               const int* __restrict__ csr,
                                               const float* __restrict__ hs1,
                                               const float* __restrict__ dis,
                                               const float* __restrict__ b1,
                                               float* __restrict__ hs2, int n) {
    int node = blockIdx.x * 4 + (threadIdx.x >> 6);
    int ch = threadIdx.x & 63;
    if (node >= n) return;
    int beg = rowptr[node], end = rowptr[node + 1];
    float a0 = hs1[(size_t)node * 64 + ch], a1 = 0.f, a2 = 0.f, a3 = 0.f;
    int k = beg;
    for (; k + 4 <= end; k += 4) {
        int s0 = csr[k], s1 = csr[k + 1], s2 = csr[k + 2], s3 = csr[k + 3];
        a0 += hs1[(size_t)s0 * 64 + ch];
        a1 += hs1[(size_t)s1 * 64 + ch];
        a2 += hs1[(size_t)s2 * 64 + ch];
        a3 += hs1[(size_t)s3 * 64 + ch];
    }
    for (; k < end; ++k) a0 += hs1[(size_t)csr[k] * 64 + ch];
    float d = dis[node];
    float v = d * ((a0 + a1) + (a2 + a3)) + b1[ch];
    hs2[(size_t)node * 64 + ch] = d * (v > 0.f ? v : 0.f);
}

// pull: gagg[i] = dis[i]*(hs2[i]+sum)
__global__ __launch_bounds__(256) void k_pull2(const int* __restrict__ rowptr,
                                               const int* __restrict__ csr,
                                               const float* __restrict__ hs2,
                                               const float* __restrict__ dis,
                                               float* __restrict__ gagg, int n) {
    int node = blockIdx.x * 4 + (threadIdx.x >> 6);
    int ch = threadIdx.x & 63;
    if (node >= n) return;
    int beg = rowptr[node], end = rowptr[node + 1];
    float a0 = hs2[(size_t)node * 64 + ch], a1 = 0.f, a2 = 0.f, a3 = 0.f;
    int k = beg;
    for (; k + 4 <= end; k += 4) {
        int s0 = csr[k], s1 = csr[k + 1], s2 = csr[k + 2], s3 = csr[k + 3];
        a0 += hs2[(size_t)s0 * 64 + ch];
        a1 += hs2[(size_t)s1 * 64 + ch];
        a2 += hs2[(size_t)s2 * 64 + ch];
        a3 += hs2[(size_t)s3 * 64 + ch];
    }
    for (; k < end; ++k) a0 += hs2[(size_t)csr[k] * 64 + ch];
    gagg[(size_t)node * 64 + ch] = dis[node] * ((a0 + a1) + (a2 + a3));
}

// g[n,64] @ {W2,W3}[64,32] + bias -> out = mu ++ logvar. 64 rows/block.
__global__ __launch_bounds__(256) void k_gemm23(const float* __restrict__ g,
                                                const float* __restrict__ W2,
                                                const float* __restrict__ b2,
                                                const float* __restrict__ W3,
                                                const float* __restrict__ b3,
                                                float* __restrict__ out, int n) {
    __shared__ float w2[64 * 32], w3[64 * 32];
    for (int i = threadIdx.x; i < 64 * 32; i += 256) { w2[i] = W2[i]; w3[i] = W3[i]; }
    __syncthreads();
    int col = threadIdx.x & 31;
    int rbase = blockIdx.x * 64 + (threadIdx.x >> 5);
    for (int rr = 0; rr < 64; rr += 8) {
        int row = rbase + rr;
        if (row >= n) break;
        const float* gr = g + (size_t)row * 64;
        float a2 = 0.f, a3 = 0.f;
#pragma unroll
        for (int k = 0; k < 64; ++k) {
            float gv = gr[k];
            a2 += gv * w2[k * 32 + col];
            a3 += gv * w3[k * 32 + col];
        }
        out[(size_t)row * 32 + col] = a2 + b2[col];
        out[(size_t)n * 32 + (size_t)row * 32 + col] = a3 + b3[col];
    }
}

extern "C" void kernel_launch(void* const* d_in, const int* in_sizes, int n_in,
                              void* d_out, int out_size, void* d_ws, size_t ws_size,
                              hipStream_t stream) {
    const float* x  = (const float*)d_in[0];
    const int*   ei = (const int*)d_in[1];   // int32 per harness contract
    const float* W1 = (const float*)d_in[2];
    const float* b1 = (const float*)d_in[3];
    const float* W2 = (const float*)d_in[4];
    const float* b2 = (const float*)d_in[5];
    const float* W3 = (const float*)d_in[6];
    const float* b3 = (const float*)d_in[7];

    int n = in_sizes[0] / 128;   // 50000
    int e = in_sizes[1] / 2;     // 1600000
    int nb = (n + BKT - 1) / BKT;
    const int* row = ei;
    const int* col = ei + e;

    float* fws  = (float*)d_ws;
    float* dis  = fws;                        // n
    float* hs1  = fws + n;                    // n*64  (binbuf aliases its head)
    float* hs2  = hs1 + (size_t)n * 64;       // n*64
    float* gagg = hs1;                        // alias: hs1 dead after pull1
    int* binbuf = (int*)hs1;                  // e ints, dead before gemm1
    int* cnt    = (int*)(hs2 + (size_t)n * 64);  // n
    int* rowptr = cnt + n;                    // n+1
    int* bcur   = rowptr + n + 1;             // nb
    int* csr    = bcur + nb;                  // e
    float* out  = (float*)d_out;

    dim3 blk(256);
    hipMemsetAsync(cnt, 0, (size_t)n * 4, stream);
    k_count<<<(e + 255) / 256, blk, 0, stream>>>(col, cnt, e);
    k_dis<<<(n + 255) / 256, blk, 0, stream>>>(cnt, dis, n);
    k_scan<<<1, 1024, 0, stream>>>(cnt, rowptr, n);
    k_bcur<<<(nb + 255) / 256, blk, 0, stream>>>(rowptr, bcur, nb);
    k_bin<<<(e + 255) / 256, blk, 0, stream>>>(row, col, bcur, binbuf, e);
    k_fill_bucket<<<nb, blk, 0, stream>>>(binbuf, rowptr, csr, n);

    k_gemm1<<<(n + 31) / 32, blk, 0, stream>>>(x, W1, dis, hs1, n);
    k_pull1<<<(n + 3) / 4, blk, 0, stream>>>(rowptr, csr, hs1, dis, b1, hs2, n);
    k_pull2<<<(n + 3) / 4, blk, 0, stream>>>(rowptr, csr, hs2, dis, gagg, n);
    k_gemm23<<<(n + 63) / 64, blk, 0, stream>>>(gagg, W2, b2, W3, b3, out, n);
}

// Round 5
// 305.764 us; speedup vs baseline: 2.8979x; 1.7313x over previous
//
#include <hip/hip_runtime.h>

// GCN VGAE encoder, pull-based. N=50000 (<2^16: rows pack in 16 bits), E=1.6M.
// out[i] = dis[i] * (hs[i] + sum_{j->i} hs[j]),  hs = dis .* (x@W)
// CSR build: coarse-bucket (256 nodes) counting sort with XCD-clean writes:
// every 64B line of binbuf/csr is produced by exactly one block.

#define NBMAX 256  // max coarse buckets (n <= 65536)

__global__ __launch_bounds__(256) void k_hist(const int* __restrict__ col,
                                              int* __restrict__ bcnt, int e) {
    __shared__ int h[NBMAX];
    for (int i = threadIdx.x; i < NBMAX; i += 256) h[i] = 0;
    __syncthreads();
    for (int i = blockIdx.x * 256 + threadIdx.x; i < e; i += gridDim.x * 256)
        atomicAdd(&h[col[i] >> 8], 1);
    __syncthreads();
    for (int i = threadIdx.x; i < NBMAX; i += 256)
        if (h[i]) atomicAdd(bcnt + i, h[i]);
}

// scan nb (<=256) bucket counts -> bbase[0..nb], bcur; rowptr[n] = e sentinel
__global__ __launch_bounds__(256) void k_scanb(const int* __restrict__ bcnt,
                                               int* __restrict__ bbase,
                                               int* __restrict__ bcur,
                                               int* __restrict__ rowptr,
                                               int nb, int n, int e) {
    __shared__ int s[256];
    int t = threadIdx.x;
    int v = (t < nb) ? bcnt[t] : 0;
    s[t] = v;
    __syncthreads();
    for (int off = 1; off < 256; off <<= 1) {
        int u = (t >= off) ? s[t - off] : 0;
        __syncthreads();
        s[t] += u;
        __syncthreads();
    }
    int excl = s[t] - v;
    if (t <= nb) bbase[t] = (t < nb) ? excl : e;
    if (t < nb) bcur[t] = excl;
    if (t == 0) rowptr[n] = e;
}

// each block owns an edge chunk; per-(tile,bucket) contiguous runs in binbuf
__global__ __launch_bounds__(256) void k_tilesort(const int* __restrict__ row,
                                                  const int* __restrict__ col,
                                                  int* __restrict__ bcur,
                                                  int* __restrict__ binbuf,
                                                  int e, int chunk) {
    __shared__ int lh[NBMAX];
    int t0 = blockIdx.x * chunk;
    int t1 = t0 + chunk < e ? t0 + chunk : e;
    for (int i = threadIdx.x; i < NBMAX; i += 256) lh[i] = 0;
    __syncthreads();
    for (int i = t0 + threadIdx.x; i < t1; i += 256)
        atomicAdd(&lh[col[i] >> 8], 1);
    __syncthreads();
    // reserve this tile's run in each bucket; lh becomes the running cursor
    for (int b = threadIdx.x; b < NBMAX; b += 256) {
        int c = lh[b];
        if (c) lh[b] = atomicAdd(bcur + b, c);
    }
    __syncthreads();
    for (int i = t0 + threadIdx.x; i < t1; i += 256) {
        int c = col[i];
        int pos = atomicAdd(&lh[c >> 8], 1);
        binbuf[pos] = row[i] | ((c & 255) << 16);
    }
}

// one block per bucket: per-node counts -> dis, rowptr, then csr scatter
__global__ __launch_bounds__(256) void k_build(const int* __restrict__ binbuf,
                                               const int* __restrict__ bbase,
                                               float* __restrict__ dis,
                                               int* __restrict__ rowptr,
                                               int* __restrict__ csr, int n) {
    __shared__ int lcnt[256], s[256], cur[256];
    int b = blockIdx.x;
    int t = threadIdx.x;
    int lo = bbase[b], hi = bbase[b + 1];
    int node0 = b << 8;
    int nloc = n - node0 < 256 ? n - node0 : 256;
    lcnt[t] = 0;
    __syncthreads();
    for (int k = lo + t; k < hi; k += 256)
        atomicAdd(&lcnt[(binbuf[k] >> 16) & 255], 1);
    __syncthreads();
    int v = lcnt[t];
    s[t] = v;
    __syncthreads();
    for (int off = 1; off < 256; off <<= 1) {
        int u = (t >= off) ? s[t - off] : 0;
        __syncthreads();
        s[t] += u;
        __syncthreads();
    }
    if (t < nloc) {
        int rp = lo + s[t] - v;  // exclusive prefix
        rowptr[node0 + t] = rp;
        cur[t] = rp;
        dis[node0 + t] = rsqrtf((float)v + 1.0f);  // +1 self-loop
    }
    __syncthreads();
    for (int k = lo + t; k < hi; k += 256) {
        int p = binbuf[k];
        int pos = atomicAdd(&cur[(p >> 16) & 255], 1);
        csr[pos] = p & 0xffff;
    }
}

// x[n,128] @ W[128,64], epilogue *dis  -> hs1[n,64]. 32 rows/block.
__global__ __launch_bounds__(256) void k_gemm1(const float* __restrict__ x,
                                               const float* __restrict__ W,
                                               const float* __restrict__ dis,
                                               float* __restrict__ hs1, int n) {
    __shared__ float w[128 * 64];
    for (int i = threadIdx.x; i < 128 * 64; i += 256) w[i] = W[i];
    __syncthreads();
    int ch = threadIdx.x & 63;
    int rbase = blockIdx.x * 32 + (threadIdx.x >> 6);
    for (int rr = 0; rr < 32; rr += 4) {
        int row = rbase + rr;
        if (row >= n) break;
        const float4* xr = (const float4*)(x + (size_t)row * 128);
        float acc = 0.f;
#pragma unroll
        for (int k4 = 0; k4 < 32; ++k4) {
            float4 xv = xr[k4];
            int k = k4 * 4;
            acc += xv.x * w[k * 64 + ch] + xv.y * w[(k + 1) * 64 + ch] +
                   xv.z * w[(k + 2) * 64 + ch] + xv.w * w[(k + 3) * 64 + ch];
        }
        hs1[(size_t)row * 64 + ch] = dis[row] * acc;
    }
}

// pull + relu(...+b1) + rescale: hs2[i] = dis[i]*relu(dis[i]*(hs1[i]+sum)+b1)
__global__ __launch_bounds__(256) void k_pull1(const int* __restrict__ rowptr,
                                               const int* __restrict__ csr,
                                               const float* __restrict__ hs1,
                                               const float* __restrict__ dis,
                                               const float* __restrict__ b1,
                                               float* __restrict__ hs2, int n) {
    int node = blockIdx.x * 4 + (threadIdx.x >> 6);
    int ch = threadIdx.x & 63;
    if (node >= n) return;
    int beg = rowptr[node], end = rowptr[node + 1];
    float a0 = hs1[(size_t)node * 64 + ch], a1 = 0.f, a2 = 0.f, a3 = 0.f;
    int k = beg;
    for (; k + 4 <= end; k += 4) {
        int s0 = csr[k], s1 = csr[k + 1], s2 = csr[k + 2], s3 = csr[k + 3];
        a0 += hs1[(size_t)s0 * 64 + ch];
        a1 += hs1[(size_t)s1 * 64 + ch];
        a2 += hs1[(size_t)s2 * 64 + ch];
        a3 += hs1[(size_t)s3 * 64 + ch];
    }
    for (; k < end; ++k) a0 += hs1[(size_t)csr[k] * 64 + ch];
    float d = dis[node];
    float v = d * ((a0 + a1) + (a2 + a3)) + b1[ch];
    hs2[(size_t)node * 64 + ch] = d * (v > 0.f ? v : 0.f);
}

// pull: gagg[i] = dis[i]*(hs2[i]+sum)
__global__ __launch_bounds__(256) void k_pull2(const int* __restrict__ rowptr,
                                               const int* __restrict__ csr,
                                               const float* __restrict__ hs2,
                                               const float* __restrict__ dis,
                                               float* __restrict__ gagg, int n) {
    int node = blockIdx.x * 4 + (threadIdx.x >> 6);
    int ch = threadIdx.x & 63;
    if (node >= n) return;
    int beg = rowptr[node], end = rowptr[node + 1];
    float a0 = hs2[(size_t)node * 64 + ch], a1 = 0.f, a2 = 0.f, a3 = 0.f;
    int k = beg;
    for (; k + 4 <= end; k += 4) {
        int s0 = csr[k], s1 = csr[k + 1], s2 = csr[k + 2], s3 = csr[k + 3];
        a0 += hs2[(size_t)s0 * 64 + ch];
        a1 += hs2[(size_t)s1 * 64 + ch];
        a2 += hs2[(size_t)s2 * 64 + ch];
        a3 += hs2[(size_t)s3 * 64 + ch];
    }
    for (; k < end; ++k) a0 += hs2[(size_t)csr[k] * 64 + ch];
    gagg[(size_t)node * 64 + ch] = dis[node] * ((a0 + a1) + (a2 + a3));
}

// g[n,64] @ {W2,W3}[64,32] + bias -> out = mu ++ logvar. 64 rows/block.
__global__ __launch_bounds__(256) void k_gemm23(const float* __restrict__ g,
                                                const float* __restrict__ W2,
                                                const float* __restrict__ b2,
                                                const float* __restrict__ W3,
                                                const float* __restrict__ b3,
                                                float* __restrict__ out, int n) {
    __shared__ float w2[64 * 32], w3[64 * 32];
    for (int i = threadIdx.x; i < 64 * 32; i += 256) { w2[i] = W2[i]; w3[i] = W3[i]; }
    __syncthreads();
    int col = threadIdx.x & 31;
    int rbase = blockIdx.x * 64 + (threadIdx.x >> 5);
    for (int rr = 0; rr < 64; rr += 8) {
        int row = rbase + rr;
        if (row >= n) break;
        const float* gr = g + (size_t)row * 64;
        float a2 = 0.f, a3 = 0.f;
#pragma unroll
        for (int k = 0; k < 64; ++k) {
            float gv = gr[k];
            a2 += gv * w2[k * 32 + col];
            a3 += gv * w3[k * 32 + col];
        }
        out[(size_t)row * 32 + col] = a2 + b2[col];
        out[(size_t)n * 32 + (size_t)row * 32 + col] = a3 + b3[col];
    }
}

extern "C" void kernel_launch(void* const* d_in, const int* in_sizes, int n_in,
                              void* d_out, int out_size, void* d_ws, size_t ws_size,
                              hipStream_t stream) {
    const float* x  = (const float*)d_in[0];
    const int*   ei = (const int*)d_in[1];   // int32 per harness contract
    const float* W1 = (const float*)d_in[2];
    const float* b1 = (const float*)d_in[3];
    const float* W2 = (const float*)d_in[4];
    const float* b2 = (const float*)d_in[5];
    const float* W3 = (const float*)d_in[6];
    const float* b3 = (const float*)d_in[7];

    int n = in_sizes[0] / 128;   // 50000
    int e = in_sizes[1] / 2;     // 1600000
    int nb = (n + 255) >> 8;     // 196 coarse buckets of 256 nodes
    const int* row = ei;
    const int* col = ei + e;

    float* fws  = (float*)d_ws;
    float* dis  = fws;                        // n
    float* hs1  = fws + n;                    // n*64  (binbuf aliases its head)
    float* hs2  = hs1 + (size_t)n * 64;       // n*64
    float* gagg = hs1;                        // alias: hs1 dead after pull1
    int* binbuf = (int*)hs1;                  // e ints, dead before gemm1
    int* cnt    = (int*)(hs2 + (size_t)n * 64);  // nb (bcnt)
    int* bbase  = cnt + nb;                   // nb+1
    int* bcur   = bbase + nb + 1;             // nb
    int* rowptr = bcur + nb;                  // n+1
    int* csr    = rowptr + n + 1;             // e
    float* out  = (float*)d_out;

    int chunk = (e + nb - 1) / nb;

    dim3 blk(256);
    hipMemsetAsync(cnt, 0, (size_t)nb * 4, stream);
    k_hist<<<nb, blk, 0, stream>>>(col, cnt, e);
    k_scanb<<<1, blk, 0, stream>>>(cnt, bbase, bcur, rowptr, nb, n, e);
    k_tilesort<<<nb, blk, 0, stream>>>(row, col, bcur, binbuf, e, chunk);
    k_build<<<nb, blk, 0, stream>>>(binbuf, bbase, dis, rowptr, csr, n);

    k_gemm1<<<(n + 31) / 32, blk, 0, stream>>>(x, W1, dis, hs1, n);
    k_pull1<<<(n + 3) / 4, blk, 0, stream>>>(rowptr, csr, hs1, dis, b1, hs2, n);
    k_pull2<<<(n + 3) / 4, blk, 0, stream>>>(rowptr, csr, hs2, dis, gagg, n);
    k_gemm23<<<(n + 63) / 64, blk, 0, stream>>>(gagg, W2, b2, W3, b3, out, n);
}